// Round 3
// baseline (5035.958 us; speedup 1.0000x reference)
//
#include <hip/hip_runtime.h>
#include <cstdint>

// LSTM LM: logits = LSTM(E[idx] @ Wi) @ Wo + bo
// B=16, S=256, D=256, H=512, 4H=2048, V=50257 (padded to 50304 = 393*128)
//
// Round-3 structure: FUSED recurrence + logits GEMM (k23).
//  - blocks 0..63   : producers. 4 waves each split K=512; per-step sync via
//    self-validating tagged u64 h-words (tag = t+1), sc1 L2-bypass loads/stores.
//  - blocks 64..511 : consumers. Grid-stride over 12576 (s-tile, vocab-tile)
//    128x128 logits tiles; poll per-producer flags until s-range ready; then
//    split-bf16 3-pass MFMA GEMM (A from hsC via sc1 asm loads, B from WoTP).
//  Rationale: keeps the GPU busy during the recurrence (clock boost + overlap);
//  round-2 showed 11.5 us/step with VALUBusy ~1% (idle GPU, downclocked).

typedef __attribute__((ext_vector_type(8))) short short8;
typedef __attribute__((ext_vector_type(4))) float f32x4;
typedef __attribute__((ext_vector_type(4))) unsigned int u32x4;
typedef __attribute__((ext_vector_type(4))) unsigned short ush4;

#define DEVFN static __device__ __forceinline__

DEVFN unsigned short f2bf(float f) {
    unsigned int u = __float_as_uint(f);
    return (unsigned short)((u + 0x7FFFu + ((u >> 16) & 1u)) >> 16);  // RNE
}
DEVFN float bf2f(unsigned short h) { return __uint_as_float(((unsigned int)h) << 16); }
DEVFN float sigm(float x) { return 1.0f / (1.0f + __expf(-x)); }
DEVFN float tanh_fast(float x) {
    float e = __expf(-2.0f * fabsf(x));
    float t = (1.0f - e) / (1.0f + e);
    return copysignf(t, x);
}
DEVFN f32x4 fzero() { f32x4 v = {0.f, 0.f, 0.f, 0.f}; return v; }

// 16B L2-bypass load (sc0 sc1): producer h-words and consumer hsC reads must
// bypass L1/L2 (producer stores bypass L2; stale/poisoned L2 lines are fatal).
// Values NOT ready until an s_waitcnt vmcnt(0) + sched_barrier(0) fence (rule 18).
DEVFN void aload16(u32x4& d, const void* p) {
    asm volatile("global_load_dwordx4 %0, %1, off sc0 sc1" : "=v"(d) : "v"(p));
}

// ---------------- k0: transpose + split Wo -> WoTP[50304][512] packed u32 ----------------
__global__ __launch_bounds__(256) void k0_wot(const float* __restrict__ Wo,
                                              uint32_t* __restrict__ WoTP) {
    __shared__ float tile[32][33];
    const int bx = blockIdx.x;
    const int cb = bx >> 4;          // 0..1571 (vocab tiles)
    const int kb = bx & 15;          // 0..15   (k tiles)
    const int c0 = cb * 32, k0 = kb * 32;
    const int j = threadIdx.x & 31;
    const int i0 = threadIdx.x >> 5; // 0..7
    for (int ii = i0; ii < 32; ii += 8) {
        const int c = c0 + j;
        tile[ii][j] = (c < 50257) ? Wo[(size_t)(k0 + ii) * 50257 + c] : 0.0f;
    }
    __syncthreads();
    for (int ii = i0; ii < 32; ii += 8) {
        const float v = tile[j][ii];  // Wo[k0+j][c0+ii]
        const unsigned short hi = f2bf(v);
        const unsigned short lo = f2bf(v - bf2f(hi));
        WoTP[(size_t)(c0 + ii) * 512 + k0 + j] = (((unsigned int)hi) << 16) | lo;
    }
}

// ---------------- k0b: Wh bf16-lo B-fragments: [wg][nt][q][lane] 16B each ----------------
__global__ __launch_bounds__(256) void k0b_whlo(const float* __restrict__ Wh,
                                                uint32_t* __restrict__ WLO) {
    const int tid = blockIdx.x * 256 + threadIdx.x;   // 0..131071
    const int lane = tid & 63;
    const int q    = (tid >> 6) & 15;
    const int nt   = (tid >> 10) & 1;
    const int wg   = tid >> 11;
    const int cc   = lane & 15;
    const int gcol = (cc >> 2) * 512 + wg * 8 + nt * 4 + (cc & 3);
    const int kbase = q * 32 + (lane >> 4) * 8;
    u32x4 o;
#pragma unroll
    for (int p = 0; p < 4; ++p) {
        unsigned int pair = 0;
#pragma unroll
        for (int e = 0; e < 2; ++e) {
            const int k = kbase + p * 2 + e;
            const float w = Wh[(size_t)k * 2048 + gcol];
            const unsigned short hi = f2bf(w);
            const unsigned short lo = f2bf(w - bf2f(hi));
            pair |= ((unsigned int)lo) << (e * 16);
        }
        o[p] = pair;
    }
    *(u32x4*)(WLO + (size_t)tid * 4) = o;
}

// ---------------- k1: xzH[s][b][g] = bf16( sum_d E[idx[b,s],d] * Wi[d,g] ) ---------------
__global__ __launch_bounds__(256) void k1_xz(const int* __restrict__ idx,
                                             const float* __restrict__ E,
                                             const float* __restrict__ Wi,
                                             unsigned short* __restrict__ xzH) {
    __shared__ float xs[16][256];
    const int s = blockIdx.x;
    const int t = threadIdx.x;
#pragma unroll
    for (int b = 0; b < 16; ++b) {
        const int row = idx[b * 256 + s];
        xs[b][t] = E[(size_t)row * 256 + t];
    }
    __syncthreads();
    for (int half = 0; half < 2; ++half) {
        const int g0 = half * 1024 + t * 4;
        f32x4 acc[16];
#pragma unroll
        for (int b = 0; b < 16; ++b) acc[b] = fzero();
        for (int d = 0; d < 256; ++d) {
            const f32x4 w = *(const f32x4*)&Wi[(size_t)d * 2048 + g0];
#pragma unroll
            for (int b = 0; b < 16; ++b) {
                const float xv = xs[b][d];
                acc[b] += xv * w;
            }
        }
#pragma unroll
        for (int b = 0; b < 16; ++b) {
            ush4 o;
#pragma unroll
            for (int jj = 0; jj < 4; ++jj) o[jj] = f2bf(acc[b][jj]);
            *(ush4*)&xzH[((size_t)s * 16 + b) * 2048 + g0] = o;
        }
    }
}

// ---------------- k23: fused recurrence (producers) + logits GEMM (consumers) ------------
__global__ __launch_bounds__(256, 2) void k23(const float* __restrict__ Wh,
                                              const float* __restrict__ bh,
                                              const unsigned short* __restrict__ xzH,
                                              const short8* __restrict__ WLO8,
                                              unsigned long long* __restrict__ hsT,
                                              uint32_t* __restrict__ hsC,
                                              uint32_t* __restrict__ flags,
                                              const uint32_t* __restrict__ WoTP,
                                              const float* __restrict__ bo,
                                              float* __restrict__ out) {
    __shared__ __align__(16) char smem[65536];

    if (blockIdx.x < 64) {
        // ================= PRODUCER =================
        const int wg = blockIdx.x;
        const int tid = threadIdx.x;
        const int lane = tid & 63;
        const int w = tid >> 6;          // wave 0..3: owns q = w*4 .. w*4+3 (k-range w*128..)
        const int c = lane & 15;
        const int qtr = lane >> 4;

        unsigned short* whh = (unsigned short*)smem;      // [32 cols][512 k] bf16-hi, swizzled
        float* pls = (float*)(smem + 32768);              // [2][4 waves][64 lanes][8] partials

        // stage Wh-hi slice (256 threads): l = col 0..31, seg = k-range segment
        {
            const int l = tid >> 3, seg = tid & 7;
            const int cc = l & 15, nt0 = l >> 4;
            const int gcol = (cc >> 2) * 512 + wg * 8 + nt0 * 4 + (cc & 3);
            for (int k8 = seg * 64; k8 < seg * 64 + 64; k8 += 8) {
                short8 v;
#pragma unroll
                for (int i = 0; i < 8; ++i)
                    v[i] = (short)f2bf(Wh[(size_t)(k8 + i) * 2048 + gcol]);
                const int slot = (k8 >> 3) ^ (l & 7);
                *(short8*)((char*)whh + l * 1024 + slot * 16) = v;
            }
        }
        __syncthreads();

        int gc[2];
        float bh_v[2];
#pragma unroll
        for (int nt = 0; nt < 2; ++nt) {
            gc[nt] = (c >> 2) * 512 + wg * 8 + nt * 4 + (c & 3);
            bh_v[nt] = bh[gc[nt]];
        }
        float cst[2][4];
#pragma unroll
        for (int nt = 0; nt < 2; ++nt)
#pragma unroll
            for (int r = 0; r < 4; ++r) cst[nt][r] = 0.0f;

        float xzv[2][4];
#pragma unroll
        for (int nt = 0; nt < 2; ++nt)
#pragma unroll
            for (int r = 0; r < 4; ++r)
                xzv[nt][r] = bf2f(xzH[(size_t)(qtr * 4 + r) * 2048 + gc[nt]]);

        for (int t = 0; t < 256; ++t) {
            f32x4 acc[2][2];
#pragma unroll
            for (int nt = 0; nt < 2; ++nt) { acc[nt][0] = fzero(); acc[nt][1] = fzero(); }

            if (t > 0) {
                // poll tagged h-words for this wave's k-slice (b = c, j per q)
                const unsigned long long* hrow = hsT + ((size_t)(t - 1) * 16 + c) * 512;
                u32x4 d[16];
                const unsigned tgt = (unsigned)t;   // step t-1 stored tag t
                while (true) {
#pragma unroll
                    for (int qq = 0; qq < 4; ++qq) {
                        const int kb = (w * 4 + qq) * 32 + qtr * 8;
#pragma unroll
                        for (int p = 0; p < 4; ++p)
                            aload16(d[qq * 4 + p], (const void*)(hrow + kb + p * 2));
                    }
                    asm volatile("s_waitcnt vmcnt(0)" ::: "memory");
                    __builtin_amdgcn_sched_barrier(0);
                    int ok = 1;
#pragma unroll
                    for (int i = 0; i < 16; ++i)
                        ok &= (int)((d[i][0] == tgt) & (d[i][2] == tgt));
                    if (__all(ok)) break;
                }
                // fragments + MFMA over this wave's 4 q-subtiles
#pragma unroll
                for (int qq = 0; qq < 4; ++qq) {
                    const int q = w * 4 + qq;
                    short8 ahi, alo;
#pragma unroll
                    for (int p = 0; p < 4; ++p) {
                        const unsigned h0 = d[qq * 4 + p][1], h1 = d[qq * 4 + p][3];
                        ahi[2 * p]     = (short)(h0 >> 16); alo[2 * p]     = (short)(h0 & 0xffffu);
                        ahi[2 * p + 1] = (short)(h1 >> 16); alo[2 * p + 1] = (short)(h1 & 0xffffu);
                    }
#pragma unroll
                    for (int nt = 0; nt < 2; ++nt) {
                        const int l = nt * 16 + c;
                        const short8 bhi = *(const short8*)((const char*)whh + l * 1024 +
                                                            (((q * 4 + qtr) ^ (l & 7)) << 4));
                        const short8 blo = WLO8[(((size_t)wg * 2 + nt) * 16 + q) * 64 + lane];
                        f32x4 a = acc[nt][qq & 1];
                        a = __builtin_amdgcn_mfma_f32_16x16x32_bf16(ahi, bhi, a, 0, 0, 0);
                        a = __builtin_amdgcn_mfma_f32_16x16x32_bf16(ahi, blo, a, 0, 0, 0);
                        a = __builtin_amdgcn_mfma_f32_16x16x32_bf16(alo, bhi, a, 0, 0, 0);
                        acc[nt][qq & 1] = a;
                    }
                }
            }

            // cross-wave K-reduction via LDS (double-buffered by t parity)
            float* my = pls + (t & 1) * 2048 + w * 512 + lane * 8;
            *(f32x4*)my       = acc[0][0] + acc[0][1];
            *(f32x4*)(my + 4) = acc[1][0] + acc[1][1];
            __syncthreads();
            f32x4 zs0 = fzero(), zs1 = fzero();
#pragma unroll
            for (int ww = 0; ww < 4; ++ww) {
                const float* pp = pls + (t & 1) * 2048 + ww * 512 + lane * 8;
                zs0 += *(const f32x4*)pp;
                zs1 += *(const f32x4*)(pp + 4);
            }

#pragma unroll
            for (int nt = 0; nt < 2; ++nt) {
                f32x4 z4 = (nt == 0) ? zs0 : zs1;
#pragma unroll
                for (int r = 0; r < 4; ++r) z4[r] += xzv[nt][r] + bh_v[nt];
#pragma unroll
                for (int r = 0; r < 4; ++r) {
                    const int sb = (lane & 0x33);
                    const float zi = __shfl(z4[r], sb);
                    const float zf = __shfl(z4[r], sb | 4);
                    const float zg = __shfl(z4[r], sb | 8);
                    const float zo = __shfl(z4[r], sb | 12);
                    const float iv = sigm(zi), fv = sigm(zf);
                    const float gv = tanh_fast(zg), ov = sigm(zo);
                    const float cv = fv * cst[nt][r] + iv * gv;
                    cst[nt][r] = cv;
                    const float hv = ov * tanh_fast(cv);
                    if (w == 0 && (c >> 2) == 0) {  // one owner per (b, j)
                        const unsigned short hi = f2bf(hv);
                        const unsigned short lo = f2bf(hv - bf2f(hi));
                        const unsigned packed = (((unsigned)hi) << 16) | lo;
                        const size_t ix = ((size_t)t * 16 + qtr * 4 + r) * 512 + wg * 8 + nt * 4 + c;
                        __hip_atomic_store(&hsT[ix],
                                           ((unsigned long long)packed << 32) | (unsigned long long)(t + 1),
                                           __ATOMIC_RELAXED, __HIP_MEMORY_SCOPE_AGENT);
                        __hip_atomic_store(&hsC[ix], packed,
                                           __ATOMIC_RELAXED, __HIP_MEMORY_SCOPE_AGENT);
                    }
                }
            }
            if (w == 0) {
                asm volatile("s_waitcnt vmcnt(0)" ::: "memory");
                if (lane == 0)
                    __hip_atomic_store(&flags[wg], (unsigned)(t + 1),
                                       __ATOMIC_RELAXED, __HIP_MEMORY_SCOPE_AGENT);
            }
            if (t < 255) {
#pragma unroll
                for (int nt = 0; nt < 2; ++nt)
#pragma unroll
                    for (int r = 0; r < 4; ++r)
                        xzv[nt][r] = bf2f(xzH[((size_t)(t + 1) * 16 + qtr * 4 + r) * 2048 + gc[nt]]);
            }
        }
    } else {
        // ================= CONSUMER =================
        unsigned short (*Ah)[64] = (unsigned short(*)[64])(smem);
        unsigned short (*Al)[64] = (unsigned short(*)[64])(smem + 16384);
        unsigned short (*Bh)[64] = (unsigned short(*)[64])(smem + 32768);
        unsigned short (*Bl)[64] = (unsigned short(*)[64])(smem + 49152);

        const int cid = blockIdx.x - 64;
        const int tid = threadIdx.x;
        const int lane = tid & 63;
        const int wv = tid >> 6;
        const int wr = wv >> 1, wc = wv & 1;
        const int srow = tid >> 1, shalf = tid & 1;

        for (int id = cid; id < 12576; id += 448) {
            const int s0 = id / 393;          // s-tile: rows s in [s0*8, s0*8+8), all 16 b
            const int v = id - s0 * 393;      // vocab tile
            const unsigned need = (unsigned)(s0 * 8 + 8);
            while (true) {
                const unsigned f = __hip_atomic_load(&flags[lane], __ATOMIC_RELAXED,
                                                     __HIP_MEMORY_SCOPE_AGENT);
                if (__all((int)(f >= need))) break;
                __builtin_amdgcn_s_sleep(64);
            }

            f32x4 acc[4][4];
#pragma unroll
            for (int i = 0; i < 4; ++i)
#pragma unroll
                for (int j = 0; j < 4; ++j) acc[i][j] = fzero();

            for (int kb = 0; kb < 8; ++kb) {
                __syncthreads();
                const uint32_t* sa = hsC + (size_t)(s0 * 128 + srow) * 512 + kb * 64 + shalf * 32;
                const uint32_t* sbp = WoTP + (size_t)(v * 128 + srow) * 512 + kb * 64 + shalf * 32;
                u32x4 av[8], bv[8];
#pragma unroll
                for (int g = 0; g < 4; ++g) {
                    aload16(av[2 * g], sa + g * 8);
                    aload16(av[2 * g + 1], sa + g * 8 + 4);
                }
#pragma unroll
                for (int g = 0; g < 4; ++g) {
                    bv[2 * g]     = *(const u32x4*)(sbp + g * 8);
                    bv[2 * g + 1] = *(const u32x4*)(sbp + g * 8 + 4);
                }
                asm volatile("s_waitcnt vmcnt(0)" ::: "memory");
                __builtin_amdgcn_sched_barrier(0);
#pragma unroll
                for (int g = 0; g < 4; ++g) {
                    short8 hi, lo;
#pragma unroll
                    for (int i = 0; i < 4; ++i) {
                        hi[i]     = (short)(av[2 * g][i] >> 16);
                        lo[i]     = (short)(av[2 * g][i] & 0xffffu);
                        hi[4 + i] = (short)(av[2 * g + 1][i] >> 16);
                        lo[4 + i] = (short)(av[2 * g + 1][i] & 0xffffu);
                    }
                    const int sw = ((shalf * 4 + g) ^ (srow & 7)) << 4;
                    *(short8*)((char*)Ah + srow * 128 + sw) = hi;
                    *(short8*)((char*)Al + srow * 128 + sw) = lo;
                }
#pragma unroll
                for (int g = 0; g < 4; ++g) {
                    short8 hi, lo;
#pragma unroll
                    for (int i = 0; i < 4; ++i) {
                        hi[i]     = (short)(bv[2 * g][i] >> 16);
                        lo[i]     = (short)(bv[2 * g][i] & 0xffffu);
                        hi[4 + i] = (short)(bv[2 * g + 1][i] >> 16);
                        lo[4 + i] = (short)(bv[2 * g + 1][i] & 0xffffu);
                    }
                    const int sw = ((shalf * 4 + g) ^ (srow & 7)) << 4;
                    *(short8*)((char*)Bh + srow * 128 + sw) = hi;
                    *(short8*)((char*)Bl + srow * 128 + sw) = lo;
                }
                __syncthreads();

#pragma unroll
                for (int q = 0; q < 2; ++q) {
                    short8 afh[4], afl[4], bfh[4], bfl[4];
#pragma unroll
                    for (int mi = 0; mi < 4; ++mi) {
                        const int r = wr * 64 + mi * 16 + (lane & 15);
                        const int sw = ((q * 4 + (lane >> 4)) ^ (r & 7)) << 4;
                        afh[mi] = *(const short8*)((const char*)Ah + r * 128 + sw);
                        afl[mi] = *(const short8*)((const char*)Al + r * 128 + sw);
                    }
#pragma unroll
                    for (int nj = 0; nj < 4; ++nj) {
                        const int r = wc * 64 + nj * 16 + (lane & 15);
                        const int sw = ((q * 4 + (lane >> 4)) ^ (r & 7)) << 4;
                        bfh[nj] = *(const short8*)((const char*)Bh + r * 128 + sw);
                        bfl[nj] = *(const short8*)((const char*)Bl + r * 128 + sw);
                    }
#pragma unroll
                    for (int mi = 0; mi < 4; ++mi)
#pragma unroll
                        for (int nj = 0; nj < 4; ++nj) {
                            f32x4 a = acc[mi][nj];
                            a = __builtin_amdgcn_mfma_f32_16x16x32_bf16(afh[mi], bfh[nj], a, 0, 0, 0);
                            a = __builtin_amdgcn_mfma_f32_16x16x32_bf16(afh[mi], bfl[nj], a, 0, 0, 0);
                            a = __builtin_amdgcn_mfma_f32_16x16x32_bf16(afl[mi], bfh[nj], a, 0, 0, 0);
                            acc[mi][nj] = a;
                        }
                }
            }

#pragma unroll
            for (int nj = 0; nj < 4; ++nj) {
                const int colg = v * 128 + wc * 64 + nj * 16 + (lane & 15);
                if (colg < 50257) {
                    const float bov = bo[colg];
#pragma unroll
                    for (int mi = 0; mi < 4; ++mi)
#pragma unroll
                        for (int r = 0; r < 4; ++r) {
                            const int tr = wr * 64 + mi * 16 + (lane >> 4) * 4 + r;
                            const int ss = s0 * 8 + (tr >> 4);
                            const int bb = tr & 15;
                            out[((size_t)bb * 256 + ss) * 50257 + colg] = acc[mi][nj][r] + bov;
                        }
                }
            }
        }
    }
}

// ---------------- launch ----------------------------------------------------------------
// Workspace layout (total 147,063,040 B <= proven-safe 147 MB):
#define XZH_OFF  0ull           // 256*16*2048*2  = 16,777,216  (bf16 xz)
#define HST_OFF  16777216ull    // 256*16*512*8   = 16,777,216  (tagged u64 h)
#define HSC_OFF  33554432ull    // 256*16*512*4   =  8,388,608  (packed u32 h)
#define WLO_OFF  41943040ull    // 64*2*16*64*16  =  2,097,152
#define FLG_OFF  44040192ull    // 64*4 = 256
#define WOT_OFF  44040448ull    // 50304*512*4    = 103,022,592

extern "C" void kernel_launch(void* const* d_in, const int* in_sizes, int n_in,
                              void* d_out, int out_size, void* d_ws, size_t ws_size,
                              hipStream_t stream) {
    (void)in_sizes; (void)n_in; (void)out_size; (void)ws_size;
    const int*   idx = (const int*)  d_in[0];
    const float* E   = (const float*)d_in[1];
    const float* Wi  = (const float*)d_in[2];
    const float* Wh  = (const float*)d_in[3];
    const float* bh  = (const float*)d_in[4];
    const float* Wo  = (const float*)d_in[5];
    const float* bo  = (const float*)d_in[6];
    float* out = (float*)d_out;
    char* ws = (char*)d_ws;

    unsigned short*     xzH  = (unsigned short*)    (ws + XZH_OFF);
    unsigned long long* hsT  = (unsigned long long*)(ws + HST_OFF);
    uint32_t*           hsC  = (uint32_t*)          (ws + HSC_OFF);
    uint32_t*           WLO  = (uint32_t*)          (ws + WLO_OFF);
    uint32_t*           flags= (uint32_t*)          (ws + FLG_OFF);
    uint32_t*           WoTP = (uint32_t*)          (ws + WOT_OFF);

    // clear tags + flags every call (no cross-replay reuse of sync state)
    hipMemsetAsync(ws + HST_OFF, 0, 16777216, stream);
    hipMemsetAsync(ws + FLG_OFF, 0, 256, stream);

    hipLaunchKernelGGL(k0_wot,   dim3(25152), dim3(256), 0, stream, Wo, WoTP);
    hipLaunchKernelGGL(k0b_whlo, dim3(512),   dim3(256), 0, stream, Wh, WLO);
    hipLaunchKernelGGL(k1_xz,    dim3(256),   dim3(256), 0, stream, idx, E, Wi, xzH);
    hipLaunchKernelGGL(k23,      dim3(512),   dim3(256), 0, stream,
                       Wh, bh, xzH, (const short8*)WLO, hsT, hsC, flags, WoTP, bo, out);
}

// Round 4
// 4121.854 us; speedup vs baseline: 1.2218x; 1.2218x over previous
//
#include <hip/hip_runtime.h>
#include <cstdint>

// LSTM LM: logits = LSTM(E[idx] @ Wi) @ Wo + bo
// B=16, S=256, D=256, H=512, 4H=2048, V=50257 (padded to 50304 = 393*128)
//
// Round-4 structure: fused k23, restructured.
//  - blocks 0..63   : producers — round-2's validated 1-wave recurrence
//    (96 MFMA/step, shfl gates, sc1 relaxed h-stores -> vmcnt drain -> flag),
//    h stored t-major: hsP[(t*16+b)*512 + j].
//  - blocks 64..456 : consumers — ONE vocab-tile (128 cols) per block, s0-inner:
//    B-panel (256KB of WoTP) stays L2-hot; A (hsP s-tile) read via sc1 bypass
//    loads after flag wait. Fixes round-3's 2 GB HBM re-streaming of WoTP.

typedef __attribute__((ext_vector_type(8))) short short8;
typedef __attribute__((ext_vector_type(4))) float f32x4;
typedef __attribute__((ext_vector_type(4))) unsigned int u32x4;
typedef __attribute__((ext_vector_type(4))) unsigned short ush4;

#define DEVFN static __device__ __forceinline__

DEVFN unsigned short f2bf(float f) {
    unsigned int u = __float_as_uint(f);
    return (unsigned short)((u + 0x7FFFu + ((u >> 16) & 1u)) >> 16);  // RNE
}
DEVFN float bf2f(unsigned short h) { return __uint_as_float(((unsigned int)h) << 16); }
DEVFN float sigm(float x) { return 1.0f / (1.0f + __expf(-x)); }
DEVFN float tanh_fast(float x) {
    float e = __expf(-2.0f * fabsf(x));
    float t = (1.0f - e) / (1.0f + e);
    return copysignf(t, x);
}
DEVFN f32x4 fzero() { f32x4 v = {0.f, 0.f, 0.f, 0.f}; return v; }

// 16B L1+L2-bypass load (sc0 sc1): hsP/flags are written with sc1 stores that
// bypass the (non-coherent, possibly poison-stale) L2s. Result NOT ready until
// s_waitcnt vmcnt(0) + sched_barrier(0) (rule 18).
DEVFN void aload16(u32x4& d, const void* p) {
    asm volatile("global_load_dwordx4 %0, %1, off sc0 sc1" : "=v"(d) : "v"(p));
}

// ---------------- k0: transpose + split Wo -> WoTP[50304][512] packed u32 ----------------
__global__ __launch_bounds__(256) void k0_wot(const float* __restrict__ Wo,
                                              uint32_t* __restrict__ WoTP) {
    __shared__ float tile[32][33];
    const int bx = blockIdx.x;
    const int cb = bx >> 4;          // 0..1571 (vocab tiles)
    const int kb = bx & 15;          // 0..15   (k tiles)
    const int c0 = cb * 32, k0 = kb * 32;
    const int j = threadIdx.x & 31;
    const int i0 = threadIdx.x >> 5; // 0..7
    for (int ii = i0; ii < 32; ii += 8) {
        const int c = c0 + j;
        tile[ii][j] = (c < 50257) ? Wo[(size_t)(k0 + ii) * 50257 + c] : 0.0f;
    }
    __syncthreads();
    for (int ii = i0; ii < 32; ii += 8) {
        const float v = tile[j][ii];  // Wo[k0+j][c0+ii]
        const unsigned short hi = f2bf(v);
        const unsigned short lo = f2bf(v - bf2f(hi));
        WoTP[(size_t)(c0 + ii) * 512 + k0 + j] = (((unsigned int)hi) << 16) | lo;
    }
}

// ---------------- k0b: Wh bf16-lo B-fragments: [wg][nt][q][lane] 16B each ----------------
__global__ __launch_bounds__(256) void k0b_whlo(const float* __restrict__ Wh,
                                                uint32_t* __restrict__ WLO) {
    const int tid = blockIdx.x * 256 + threadIdx.x;   // 0..131071
    const int lane = tid & 63;
    const int q    = (tid >> 6) & 15;
    const int nt   = (tid >> 10) & 1;
    const int wg   = tid >> 11;
    const int cc   = lane & 15;
    const int gcol = (cc >> 2) * 512 + wg * 8 + nt * 4 + (cc & 3);
    const int kbase = q * 32 + (lane >> 4) * 8;
    u32x4 o;
#pragma unroll
    for (int p = 0; p < 4; ++p) {
        unsigned int pair = 0;
#pragma unroll
        for (int e = 0; e < 2; ++e) {
            const int k = kbase + p * 2 + e;
            const float w = Wh[(size_t)k * 2048 + gcol];
            const unsigned short hi = f2bf(w);
            const unsigned short lo = f2bf(w - bf2f(hi));
            pair |= ((unsigned int)lo) << (e * 16);
        }
        o[p] = pair;
    }
    *(u32x4*)(WLO + (size_t)tid * 4) = o;
}

// ---------------- k1: xzH[s][b][g] = bf16( sum_d E[idx[b,s],d] * Wi[d,g] ) ---------------
__global__ __launch_bounds__(256) void k1_xz(const int* __restrict__ idx,
                                             const float* __restrict__ E,
                                             const float* __restrict__ Wi,
                                             unsigned short* __restrict__ xzH) {
    __shared__ float xs[16][256];
    const int s = blockIdx.x;
    const int t = threadIdx.x;
#pragma unroll
    for (int b = 0; b < 16; ++b) {
        const int row = idx[b * 256 + s];
        xs[b][t] = E[(size_t)row * 256 + t];
    }
    __syncthreads();
    for (int half = 0; half < 2; ++half) {
        const int g0 = half * 1024 + t * 4;
        f32x4 acc[16];
#pragma unroll
        for (int b = 0; b < 16; ++b) acc[b] = fzero();
        for (int d = 0; d < 256; ++d) {
            const f32x4 w = *(const f32x4*)&Wi[(size_t)d * 2048 + g0];
#pragma unroll
            for (int b = 0; b < 16; ++b) {
                const float xv = xs[b][d];
                acc[b] += xv * w;
            }
        }
#pragma unroll
        for (int b = 0; b < 16; ++b) {
            ush4 o;
#pragma unroll
            for (int jj = 0; jj < 4; ++jj) o[jj] = f2bf(acc[b][jj]);
            *(ush4*)&xzH[((size_t)s * 16 + b) * 2048 + g0] = o;
        }
    }
}

// ---------------- k23: fused recurrence (producers) + logits GEMM (consumers) ------------
__global__ __launch_bounds__(256, 2) void k23(const float* __restrict__ Wh,
                                              const float* __restrict__ bh,
                                              const unsigned short* __restrict__ xzH,
                                              const short8* __restrict__ WLO8,
                                              uint32_t* __restrict__ hsP,
                                              const uint32_t* __restrict__ zeroh,
                                              uint32_t* __restrict__ flags,
                                              const uint32_t* __restrict__ WoTP,
                                              const float* __restrict__ bo,
                                              float* __restrict__ out) {
    __shared__ __align__(16) char smem[65536];

    if (blockIdx.x < 64) {
        // ================= PRODUCER (round-2 validated 1-wave pipeline) =================
        const int wg = blockIdx.x;
        const int tid = threadIdx.x;

        unsigned short* whh = (unsigned short*)smem;   // [32 cols][512 k] bf16-hi, swizzled

        // stage Wh-hi slice with all 256 threads, then waves 1..3 exit
        {
            const int l = tid >> 3, seg = tid & 7;     // l: col 0..31, seg: k segment
            const int cc = l & 15, nt0 = l >> 4;
            const int gcol = (cc >> 2) * 512 + wg * 8 + nt0 * 4 + (cc & 3);
            for (int k8 = seg * 64; k8 < seg * 64 + 64; k8 += 8) {
                short8 v;
#pragma unroll
                for (int i = 0; i < 8; ++i)
                    v[i] = (short)f2bf(Wh[(size_t)(k8 + i) * 2048 + gcol]);
                const int slot = (k8 >> 3) ^ (l & 7);
                *(short8*)((char*)whh + l * 1024 + slot * 16) = v;
            }
        }
        __syncthreads();
        if (tid >= 64) return;

        const int lane = tid;
        const int c = lane & 15;
        const int qtr = lane >> 4;

        int gc[2];
        float bh_v[2];
#pragma unroll
        for (int nt = 0; nt < 2; ++nt) {
            gc[nt] = (c >> 2) * 512 + wg * 8 + nt * 4 + (c & 3);
            bh_v[nt] = bh[gc[nt]];
        }
        float cst[2][4];
#pragma unroll
        for (int nt = 0; nt < 2; ++nt)
#pragma unroll
            for (int r = 0; r < 4; ++r) cst[nt][r] = 0.0f;

        float xzv[2][4];
#pragma unroll
        for (int nt = 0; nt < 2; ++nt)
#pragma unroll
            for (int r = 0; r < 4; ++r)
                xzv[nt][r] = bf2f(xzH[(size_t)(qtr * 4 + r) * 2048 + gc[nt]]);

        const uint32_t* flg = flags + lane;

        for (int t = 0; t < 256; ++t) {
            if (t > 0) {
                while (true) {
                    const uint32_t v = __hip_atomic_load(flg, __ATOMIC_RELAXED,
                                                         __HIP_MEMORY_SCOPE_AGENT);
                    if (__all((int)(v >= (uint32_t)t))) break;
                }
                __builtin_amdgcn_sched_barrier(0);
            }

            const uint32_t* hbase = (t == 0)
                ? (zeroh + (size_t)c * 512)
                : (hsP + ((size_t)(t - 1) * 16 + c) * 512);

            f32x4 acc[2][2];
#pragma unroll
            for (int nt = 0; nt < 2; ++nt) { acc[nt][0] = fzero(); acc[nt][1] = fzero(); }

#pragma unroll
            for (int q = 0; q < 16; ++q) {
                const int kb = q * 32 + qtr * 8;
                const unsigned long long* hb64 = (const unsigned long long*)(hbase + kb);
                unsigned long long d[4];
#pragma unroll
                for (int i = 0; i < 4; ++i)
                    d[i] = __hip_atomic_load(hb64 + i, __ATOMIC_RELAXED,
                                             __HIP_MEMORY_SCOPE_AGENT);
                short8 ahi, alo;
#pragma unroll
                for (int i = 0; i < 4; ++i) {
                    const uint32_t wlo32 = (uint32_t)d[i];
                    const uint32_t whi32 = (uint32_t)(d[i] >> 32);
                    ahi[2 * i]     = (short)(wlo32 >> 16); alo[2 * i]     = (short)(wlo32 & 0xffffu);
                    ahi[2 * i + 1] = (short)(whi32 >> 16); alo[2 * i + 1] = (short)(whi32 & 0xffffu);
                }
#pragma unroll
                for (int nt = 0; nt < 2; ++nt) {
                    const int l = nt * 16 + c;
                    const short8 bhi = *(const short8*)((const char*)whh + l * 1024 +
                                                        (((q * 4 + qtr) ^ (l & 7)) << 4));
                    const short8 blo = WLO8[(((size_t)wg * 2 + nt) * 16 + q) * 64 + lane];
                    f32x4 a = acc[nt][q & 1];
                    a = __builtin_amdgcn_mfma_f32_16x16x32_bf16(ahi, bhi, a, 0, 0, 0);
                    a = __builtin_amdgcn_mfma_f32_16x16x32_bf16(ahi, blo, a, 0, 0, 0);
                    a = __builtin_amdgcn_mfma_f32_16x16x32_bf16(alo, bhi, a, 0, 0, 0);
                    acc[nt][q & 1] = a;
                }
            }

#pragma unroll
            for (int nt = 0; nt < 2; ++nt) {
                f32x4 z4 = acc[nt][0] + acc[nt][1];
#pragma unroll
                for (int r = 0; r < 4; ++r) z4[r] += xzv[nt][r] + bh_v[nt];
#pragma unroll
                for (int r = 0; r < 4; ++r) {
                    const int sb = (lane & 0x33);
                    const float zi = __shfl(z4[r], sb);
                    const float zf = __shfl(z4[r], sb | 4);
                    const float zg = __shfl(z4[r], sb | 8);
                    const float zo = __shfl(z4[r], sb | 12);
                    const float iv = sigm(zi), fv = sigm(zf);
                    const float gv = tanh_fast(zg), ov = sigm(zo);
                    const float cv = fv * cst[nt][r] + iv * gv;
                    cst[nt][r] = cv;
                    const float hv = ov * tanh_fast(cv);
                    if ((c >> 2) == 0) {  // one owner lane per (b, j)
                        const unsigned short hi = f2bf(hv);
                        const unsigned short lo = f2bf(hv - bf2f(hi));
                        const uint32_t packed = (((uint32_t)hi) << 16) | lo;
                        __hip_atomic_store(
                            &hsP[((size_t)t * 16 + qtr * 4 + r) * 512 + wg * 8 + nt * 4 + c],
                            packed, __ATOMIC_RELAXED, __HIP_MEMORY_SCOPE_AGENT);
                    }
                }
            }

            // own h-stores at coherence point before flag becomes visible
            asm volatile("s_waitcnt vmcnt(0)" ::: "memory");
            if (lane == 0)
                __hip_atomic_store(&flags[wg], (uint32_t)(t + 1), __ATOMIC_RELAXED,
                                   __HIP_MEMORY_SCOPE_AGENT);

            if (t < 255) {
#pragma unroll
                for (int nt = 0; nt < 2; ++nt)
#pragma unroll
                    for (int r = 0; r < 4; ++r)
                        xzv[nt][r] = bf2f(xzH[((size_t)(t + 1) * 16 + qtr * 4 + r) * 2048 + gc[nt]]);
            }
        }
    } else {
        // ================= CONSUMER: one vocab-tile per block, s0-inner =================
        unsigned short (*Ah)[64] = (unsigned short(*)[64])(smem);
        unsigned short (*Al)[64] = (unsigned short(*)[64])(smem + 16384);
        unsigned short (*Bh)[64] = (unsigned short(*)[64])(smem + 32768);
        unsigned short (*Bl)[64] = (unsigned short(*)[64])(smem + 49152);

        const int v = blockIdx.x - 64;    // 0..392, fixed vocab tile for this block
        const int tid = threadIdx.x;
        const int lane = tid & 63;
        const int wv = tid >> 6;
        const int wr = wv >> 1, wc = wv & 1;
        const int srow = tid >> 1, shalf = tid & 1;

        for (int s0 = 0; s0 < 32; ++s0) {
            const unsigned need = (unsigned)(s0 * 8 + 8);
            while (true) {
                const unsigned f = __hip_atomic_load(&flags[lane], __ATOMIC_RELAXED,
                                                     __HIP_MEMORY_SCOPE_AGENT);
                if (__all((int)(f >= need))) break;
                __builtin_amdgcn_s_sleep(32);
            }

            f32x4 acc[4][4];
#pragma unroll
            for (int i = 0; i < 4; ++i)
#pragma unroll
                for (int j = 0; j < 4; ++j) acc[i][j] = fzero();

            for (int kb = 0; kb < 8; ++kb) {
                __syncthreads();
                const uint32_t* sa = hsP + (size_t)(s0 * 128 + srow) * 512 + kb * 64 + shalf * 32;
                const uint32_t* sbp = WoTP + (size_t)(v * 128 + srow) * 512 + kb * 64 + shalf * 32;
                u32x4 av[8], bv[8];
#pragma unroll
                for (int g = 0; g < 4; ++g) {
                    aload16(av[2 * g], sa + g * 8);
                    aload16(av[2 * g + 1], sa + g * 8 + 4);
                }
#pragma unroll
                for (int g = 0; g < 4; ++g) {
                    bv[2 * g]     = *(const u32x4*)(sbp + g * 8);
                    bv[2 * g + 1] = *(const u32x4*)(sbp + g * 8 + 4);
                }
                asm volatile("s_waitcnt vmcnt(0)" ::: "memory");
                __builtin_amdgcn_sched_barrier(0);
#pragma unroll
                for (int g = 0; g < 4; ++g) {
                    short8 hi, lo;
#pragma unroll
                    for (int i = 0; i < 4; ++i) {
                        hi[i]     = (short)(av[2 * g][i] >> 16);
                        lo[i]     = (short)(av[2 * g][i] & 0xffffu);
                        hi[4 + i] = (short)(av[2 * g + 1][i] >> 16);
                        lo[4 + i] = (short)(av[2 * g + 1][i] & 0xffffu);
                    }
                    const int sw = ((shalf * 4 + g) ^ (srow & 7)) << 4;
                    *(short8*)((char*)Ah + srow * 128 + sw) = hi;
                    *(short8*)((char*)Al + srow * 128 + sw) = lo;
                }
#pragma unroll
                for (int g = 0; g < 4; ++g) {
                    short8 hi, lo;
#pragma unroll
                    for (int i = 0; i < 4; ++i) {
                        hi[i]     = (short)(bv[2 * g][i] >> 16);
                        lo[i]     = (short)(bv[2 * g][i] & 0xffffu);
                        hi[4 + i] = (short)(bv[2 * g + 1][i] >> 16);
                        lo[4 + i] = (short)(bv[2 * g + 1][i] & 0xffffu);
                    }
                    const int sw = ((shalf * 4 + g) ^ (srow & 7)) << 4;
                    *(short8*)((char*)Bh + srow * 128 + sw) = hi;
                    *(short8*)((char*)Bl + srow * 128 + sw) = lo;
                }
                __syncthreads();

#pragma unroll
                for (int q = 0; q < 2; ++q) {
                    short8 afh[4], afl[4], bfh[4], bfl[4];
#pragma unroll
                    for (int mi = 0; mi < 4; ++mi) {
                        const int r = wr * 64 + mi * 16 + (lane & 15);
                        const int sw = ((q * 4 + (lane >> 4)) ^ (r & 7)) << 4;
                        afh[mi] = *(const short8*)((const char*)Ah + r * 128 + sw);
                        afl[mi] = *(const short8*)((const char*)Al + r * 128 + sw);
                    }
#pragma unroll
                    for (int nj = 0; nj < 4; ++nj) {
                        const int r = wc * 64 + nj * 16 + (lane & 15);
                        const int sw = ((q * 4 + (lane >> 4)) ^ (r & 7)) << 4;
                        bfh[nj] = *(const short8*)((const char*)Bh + r * 128 + sw);
                        bfl[nj] = *(const short8*)((const char*)Bl + r * 128 + sw);
                    }
#pragma unroll
                    for (int mi = 0; mi < 4; ++mi)
#pragma unroll
                        for (int nj = 0; nj < 4; ++nj) {
                            f32x4 a = acc[mi][nj];
                            a = __builtin_amdgcn_mfma_f32_16x16x32_bf16(afh[mi], bfh[nj], a, 0, 0, 0);
                            a = __builtin_amdgcn_mfma_f32_16x16x32_bf16(afh[mi], bfl[nj], a, 0, 0, 0);
                            a = __builtin_amdgcn_mfma_f32_16x16x32_bf16(afl[mi], bfh[nj], a, 0, 0, 0);
                            acc[mi][nj] = a;
                        }
                }
            }

#pragma unroll
            for (int nj = 0; nj < 4; ++nj) {
                const int colg = v * 128 + wc * 64 + nj * 16 + (lane & 15);
                if (colg < 50257) {
                    const float bov = bo[colg];
#pragma unroll
                    for (int mi = 0; mi < 4; ++mi)
#pragma unroll
                        for (int r = 0; r < 4; ++r) {
                            const int tr = wr * 64 + mi * 16 + (lane >> 4) * 4 + r;
                            const int ss = s0 * 8 + (tr >> 4);
                            const int bb = tr & 15;
                            out[((size_t)bb * 256 + ss) * 50257 + colg] = acc[mi][nj][r] + bov;
                        }
                }
            }
        }
    }
}

// ---------------- launch ----------------------------------------------------------------
// Workspace layout (total ~130 MB <= proven-safe 147 MB):
#define XZH_OFF  0ull           // 256*16*2048*2  = 16,777,216  (bf16 xz)
#define HSP_OFF  16777216ull    // 256*16*512*4   =  8,388,608  (packed u32 h, t-major)
#define ZERO_OFF 25165824ull    // 16*512*4       =     32,768
#define FLG_OFF  25198592ull    // 64*4 = 256
#define WLO_OFF  25198848ull    // 64*2*16*64*16  =  2,097,152
#define WOT_OFF  27296000ull    // 50304*512*4    = 103,022,592

extern "C" void kernel_launch(void* const* d_in, const int* in_sizes, int n_in,
                              void* d_out, int out_size, void* d_ws, size_t ws_size,
                              hipStream_t stream) {
    (void)in_sizes; (void)n_in; (void)out_size; (void)ws_size;
    const int*   idx = (const int*)  d_in[0];
    const float* E   = (const float*)d_in[1];
    const float* Wi  = (const float*)d_in[2];
    const float* Wh  = (const float*)d_in[3];
    const float* bh  = (const float*)d_in[4];
    const float* Wo  = (const float*)d_in[5];
    const float* bo  = (const float*)d_in[6];
    float* out = (float*)d_out;
    char* ws = (char*)d_ws;

    unsigned short* xzH   = (unsigned short*)(ws + XZH_OFF);
    uint32_t*       hsP   = (uint32_t*)      (ws + HSP_OFF);
    uint32_t*       zeroh = (uint32_t*)      (ws + ZERO_OFF);
    uint32_t*       flags = (uint32_t*)      (ws + FLG_OFF);
    uint32_t*       WLO   = (uint32_t*)      (ws + WLO_OFF);
    uint32_t*       WoTP  = (uint32_t*)      (ws + WOT_OFF);

    // zero h(-1) block + flags each call (contiguous region; no cross-replay state)
    hipMemsetAsync(ws + ZERO_OFF, 0, 33024, stream);

    hipLaunchKernelGGL(k0_wot,   dim3(25152), dim3(256), 0, stream, Wo, WoTP);
    hipLaunchKernelGGL(k0b_whlo, dim3(512),   dim3(256), 0, stream, Wh, WLO);
    hipLaunchKernelGGL(k1_xz,    dim3(256),   dim3(256), 0, stream, idx, E, Wi, xzH);
    hipLaunchKernelGGL(k23,      dim3(457),   dim3(256), 0, stream,
                       Wh, bh, xzH, (const short8*)WLO, hsP, zeroh, flags, WoTP, bo, out);
}